// Round 9
// baseline (189.682 us; speedup 1.0000x reference)
//
#include <hip/hip_runtime.h>
#include <hip/hip_cooperative_groups.h>
#include <math.h>

namespace cg = cooperative_groups;

#define N 8192
#define D 256
#define TILE 128
#define NT (N / TILE)                  // 64 tiles per dim
#define NTILES (NT * (NT + 1) / 2)     // 2080 triangular tiles
#define NPREP (N / 4)                  // 2048 prep blocks (fallback)
#define NCOOP 256                      // cooperative grid: 1 block/CU -> co-residency guaranteed
#define LOG2E 1.4426950408889634f
#define GROUP_SZ 4096                  // bytes per 16-row fragment-major fp8 group (16*D)

#define GLOBAL_AS __attribute__((address_space(1)))
#define LDS_AS    __attribute__((address_space(3)))

typedef float f32x4 __attribute__((ext_vector_type(4)));
typedef int   i32x4 __attribute__((ext_vector_type(4)));
typedef int   i32x8 __attribute__((ext_vector_type(8)));

// ws layout:
//   offset 0       : float pA_fb[NTILES]   (fallback)   (8320 B)
//   offset 12288   : float pB_fb[NPREP]    (fallback)   (8192 B)
//   offset 24576   : float coopA[NCOOP]                 (1024 B)
//   offset 28672   : float coopB[NCOOP]                 (1024 B)
//   offset 32768   : float sq[N]                        (32768 B)
//   offset 65536   : uchar zb8[N*D] fragment-major fp8  (2 MiB)
#define WS_PAFB_OFF 0
#define WS_PBFB_OFF 12288
#define WS_CA_OFF   24576
#define WS_CB_OFF   28672
#define WS_SQ_OFF   32768
#define WS_ZB_OFF   65536

// Fragment-major fp8 layout tuned for conflict-free ds_read_b128 after a LINEAR
// global->LDS copy: within each (group g, K-step ks) 2048-B region, lane λ's
// low 16 B live at λ*16 and high 16 B at 1024+λ*16.
__device__ __forceinline__ size_t frag_off8(int row, int k) {
    const int g = row >> 4, m = row & 15;
    const int ks = (k >> 7) & 1, q = (k >> 5) & 3, j = k & 31;
    return (size_t)g * GROUP_SZ + ks * 2048 + ((j & 16) << 6)   // 0 or 1024
         + (q << 8) + (m << 4) + (j & 15);
}

// ---------------------------------------------------------------------------
// Cooperative single-dispatch kernel: Phase A prep -> grid sync -> Phase B
// MFMA pair tiles (8-9 per block, LDS-staged, next-tile staging overlapped
// with MFMA+epilogue) -> grid sync -> Phase C final reduce on block 0.
// ---------------------------------------------------------------------------
__global__ __launch_bounds__(256) void coop_kernel(const float* __restrict__ z,
                                                   unsigned char* __restrict__ zb8,
                                                   float* __restrict__ sq,
                                                   float* __restrict__ coopA,
                                                   float* __restrict__ coopB,
                                                   float* __restrict__ out) {
    __shared__ __align__(16) unsigned char As[32768];
    __shared__ __align__(16) unsigned char Bs[32768];

    const int t = threadIdx.x;
    const int lane = t & 63, wave = t >> 6;
    const int bid = blockIdx.x;

    // ---------------- Phase A: prep (32 rows per block) ----------------
    {
        float eb = 0.f;
        #pragma unroll
        for (int it = 0; it < 8; ++it) {
            const int row = bid * 32 + wave * 8 + it;
            float4 v = ((const float4*)(z + (size_t)row * D))[lane];
            unsigned p = __builtin_amdgcn_cvt_pk_fp8_f32(v.x, v.y, 0u, false);
            p = __builtin_amdgcn_cvt_pk_fp8_f32(v.z, v.w, p, true);
            *(unsigned*)(zb8 + frag_off8(row, lane * 4)) = p;
            float s = v.x * v.x + v.y * v.y + v.z * v.z + v.w * v.w;
            #pragma unroll
            for (int off = 32; off > 0; off >>= 1) s += __shfl_xor(s, off, 64);
            if (lane == 0) { sq[row] = s; eb += __expf(-0.25f * s); }
        }
        float* red = (float*)As;
        if (lane == 0) red[wave] = eb;
        __syncthreads();
        if (t == 0) coopB[bid] = red[0] + red[1] + red[2] + red[3];
    }
    __threadfence();
    cg::this_grid().sync();

    // ---------------- Phase B: pair tiles, strided ----------------
    const int wi = wave >> 1, wj = wave & 1;     // 2x2 wave grid, 64x64 per wave
    const int col = lane & 15, q = lane >> 4;
    float total = 0.f;

    #define STAGE(TL)  do {                                                        \
        int sbi = 0, srem = (TL);                                                  \
        while (srem >= NT - sbi) { srem -= NT - sbi; ++sbi; }                      \
        const int sbj = sbi + srem;                                                \
        const unsigned char* sA = zb8 + (size_t)(sbi * 8) * GROUP_SZ;              \
        const unsigned char* sB = zb8 + (size_t)(sbj * 8) * GROUP_SZ;              \
        _Pragma("unroll")                                                          \
        for (int i_ = 0; i_ < 8; ++i_) {                                           \
            const int off_ = (i_ * 256 + t) * 16;                                  \
            __builtin_amdgcn_global_load_lds((const GLOBAL_AS unsigned int*)(sA + off_), \
                                             (LDS_AS unsigned int*)(As + off_), 16, 0, 0); \
            __builtin_amdgcn_global_load_lds((const GLOBAL_AS unsigned int*)(sB + off_), \
                                             (LDS_AS unsigned int*)(Bs + off_), 16, 0, 0); \
        }                                                                          \
    } while (0)

    STAGE(bid);   // first tile
    for (int tile = bid; tile < NTILES; tile += NCOOP) {
        int bi = 0, rem = tile;
        while (rem >= NT - bi) { rem -= NT - bi; ++bi; }
        const int bj = bi + rem;
        const int i0 = bi * TILE, j0 = bj * TILE;

        f32x4 acc[4][4];
        #pragma unroll
        for (int mt = 0; mt < 4; ++mt)
            #pragma unroll
            for (int nt = 0; nt < 4; ++nt)
                acc[mt][nt] = (f32x4){0.f, 0.f, 0.f, 0.f};

        __syncthreads();   // staging for this tile drained (vmcnt(0) before barrier)

        i32x8 af[4], bf[4];
        // ks = 0 fragments + MFMAs
        #pragma unroll
        for (int x = 0; x < 4; ++x) {
            const unsigned char* a = As + (wi * 4 + x) * GROUP_SZ + lane * 16;
            i32x4 lo = *(const i32x4*)a;
            i32x4 hi = *(const i32x4*)(a + 1024);
            af[x] = __builtin_shufflevector(lo, hi, 0, 1, 2, 3, 4, 5, 6, 7);
            const unsigned char* b = Bs + (wj * 4 + x) * GROUP_SZ + lane * 16;
            i32x4 blo = *(const i32x4*)b;
            i32x4 bhi = *(const i32x4*)(b + 1024);
            bf[x] = __builtin_shufflevector(blo, bhi, 0, 1, 2, 3, 4, 5, 6, 7);
        }
        #pragma unroll
        for (int mt = 0; mt < 4; ++mt)
            #pragma unroll
            for (int nt = 0; nt < 4; ++nt)
                acc[mt][nt] = __builtin_amdgcn_mfma_scale_f32_16x16x128_f8f6f4(
                    af[mt], bf[nt], acc[mt][nt], 0, 0, 0, 127, 0, 127);
        // ks = 1 fragments (finish all LDS reads before releasing the buffers)
        #pragma unroll
        for (int x = 0; x < 4; ++x) {
            const unsigned char* a = As + (wi * 4 + x) * GROUP_SZ + 2048 + lane * 16;
            i32x4 lo = *(const i32x4*)a;
            i32x4 hi = *(const i32x4*)(a + 1024);
            af[x] = __builtin_shufflevector(lo, hi, 0, 1, 2, 3, 4, 5, 6, 7);
            const unsigned char* b = Bs + (wj * 4 + x) * GROUP_SZ + 2048 + lane * 16;
            i32x4 blo = *(const i32x4*)b;
            i32x4 bhi = *(const i32x4*)(b + 1024);
            bf[x] = __builtin_shufflevector(blo, bhi, 0, 1, 2, 3, 4, 5, 6, 7);
        }
        __syncthreads();   // all waves' LDS reads complete -> buffers free
        if (tile + NCOOP < NTILES) STAGE(tile + NCOOP);   // overlaps MFMA+epilogue
        #pragma unroll
        for (int mt = 0; mt < 4; ++mt)
            #pragma unroll
            for (int nt = 0; nt < 4; ++nt)
                acc[mt][nt] = __builtin_amdgcn_mfma_scale_f32_16x16x128_f8f6f4(
                    af[mt], bf[nt], acc[mt][nt], 0, 0, 0, 127, 0, 127);

        // epilogue: exp(-0.5*dist^2) = exp2(acc*log2e + ci + cj)
        float cj[4];
        #pragma unroll
        for (int nt = 0; nt < 4; ++nt)
            cj[nt] = -0.5f * LOG2E * sq[j0 + wj * 64 + nt * 16 + col];

        float local = 0.f;
        if (bi != bj) {
            // off-diagonal: dist^2 >> 0 (exp underflows to 0 in both ref and kernel)
            #pragma unroll
            for (int mt = 0; mt < 4; ++mt)
                #pragma unroll
                for (int r = 0; r < 4; ++r) {
                    const float ci = -0.5f * LOG2E * sq[i0 + wi * 64 + mt * 16 + q * 4 + r];
                    #pragma unroll
                    for (int nt = 0; nt < 4; ++nt)
                        local += exp2f(fmaf(acc[mt][nt][r], LOG2E, ci) + cj[nt]);
                }
            local *= 2.f;   // counts for both triangles
        } else {
            // diagonal tile: clamp and force exact 1.0 on the true diagonal
            #pragma unroll
            for (int mt = 0; mt < 4; ++mt)
                #pragma unroll
                for (int r = 0; r < 4; ++r) {
                    const int li = wi * 64 + mt * 16 + q * 4 + r;
                    const float ci = -0.5f * LOG2E * sq[i0 + li];
                    #pragma unroll
                    for (int nt = 0; nt < 4; ++nt) {
                        const int lj = wj * 64 + nt * 16 + col;
                        float arg = fminf(fmaf(acc[mt][nt][r], LOG2E, ci) + cj[nt], 0.f);
                        local += (li == lj) ? 1.0f : exp2f(arg);
                    }
                }
        }
        total += local;
    }
    #undef STAGE

    #pragma unroll
    for (int off = 32; off > 0; off >>= 1) total += __shfl_xor(total, off, 64);
    __syncthreads();                     // all waves past their LDS reads
    {
        float* red = (float*)As;
        if (lane == 0) red[wave] = total;
        __syncthreads();
        if (t == 0) coopA[bid] = red[0] + red[1] + red[2] + red[3];
    }
    __threadfence();
    cg::this_grid().sync();

    // ---------------- Phase C: final reduce (block 0) ----------------
    if (bid == 0) {
        double* dred = (double*)As;
        double sa = (double)coopA[t];    // NCOOP == blockDim == 256
        double sb = (double)coopB[t];
        #pragma unroll
        for (int off = 32; off > 0; off >>= 1) {
            sa += __shfl_xor(sa, off, 64);
            sb += __shfl_xor(sb, off, 64);
        }
        if (lane == 0) { dred[wave] = sa; dred[4 + wave] = sb; }
        __syncthreads();
        if (t == 0) {
            double A = dred[0] + dred[1] + dred[2] + dred[3];
            double B = dred[4] + dred[5] + dred[6] + dred[7];
            double term_a = A / ((double)N * (double)N);
            double coeff_b = ldexp(1.0, -128);               // 1/2^128
            double term_c = 1.0;
            for (int i = 0; i < 128; ++i) term_c /= 3.0;     // 3^-128
            out[0] = (float)(term_a - 2.0 * coeff_b * (B / (double)N) + term_c);
        }
    }
}

// ---------------------------------------------------------------------------
// Fallback path: round-8's proven 3-kernel sequence (used only if the
// cooperative launch is rejected).
// ---------------------------------------------------------------------------
__global__ __launch_bounds__(256) void prep_kernel(const float* __restrict__ z,
                                                   unsigned char* __restrict__ zb8,
                                                   float* __restrict__ sq,
                                                   float* __restrict__ partialsB) {
    __shared__ float pb4[4];
    const int t = threadIdx.x;
    const int lane = t & 63;
    const int wave = t >> 6;
    const int row = blockIdx.x * 4 + wave;
    float4 v = ((const float4*)(z + (size_t)row * D))[lane];
    unsigned p = __builtin_amdgcn_cvt_pk_fp8_f32(v.x, v.y, 0u, false);
    p = __builtin_amdgcn_cvt_pk_fp8_f32(v.z, v.w, p, true);
    *(unsigned*)(zb8 + frag_off8(row, lane * 4)) = p;
    float s = v.x * v.x + v.y * v.y + v.z * v.z + v.w * v.w;
    #pragma unroll
    for (int off = 32; off > 0; off >>= 1) s += __shfl_xor(s, off, 64);
    if (lane == 0) {
        sq[row] = s;
        pb4[wave] = __expf(-0.25f * s);
    }
    __syncthreads();
    if (t == 0) partialsB[blockIdx.x] = pb4[0] + pb4[1] + pb4[2] + pb4[3];
}

__global__ __launch_bounds__(256) void pair_mfma_kernel(const unsigned char* __restrict__ zb8,
                                                        const float* __restrict__ sq,
                                                        float* __restrict__ partialsA) {
    __shared__ __align__(16) unsigned char As[32768];
    __shared__ __align__(16) unsigned char Bs[32768];

    int bi = 0, rem = blockIdx.x;
    while (rem >= NT - bi) { rem -= NT - bi; ++bi; }
    const int bj = bi + rem;
    const int i0 = bi * TILE, j0 = bj * TILE;

    const int t = threadIdx.x;
    const int lane = t & 63, wave = t >> 6;
    const int wi = wave >> 1, wj = wave & 1;
    const int col = lane & 15, q = lane >> 4;

    const unsigned char* srcA = zb8 + (size_t)(i0 >> 4) * GROUP_SZ;
    const unsigned char* srcB = zb8 + (size_t)(j0 >> 4) * GROUP_SZ;
    #pragma unroll
    for (int i = 0; i < 8; ++i) {
        const int off = (i * 256 + t) * 16;
        __builtin_amdgcn_global_load_lds((const GLOBAL_AS unsigned int*)(srcA + off),
                                         (LDS_AS unsigned int*)(As + off), 16, 0, 0);
        __builtin_amdgcn_global_load_lds((const GLOBAL_AS unsigned int*)(srcB + off),
                                         (LDS_AS unsigned int*)(Bs + off), 16, 0, 0);
    }
    __syncthreads();

    f32x4 acc[4][4];
    #pragma unroll
    for (int mt = 0; mt < 4; ++mt)
        #pragma unroll
        for (int nt = 0; nt < 4; ++nt)
            acc[mt][nt] = (f32x4){0.f, 0.f, 0.f, 0.f};

    #pragma unroll
    for (int ks = 0; ks < 2; ++ks) {
        i32x8 af[4], bf[4];
        #pragma unroll
        for (int x = 0; x < 4; ++x) {
            const unsigned char* a = As + (wi * 4 + x) * GROUP_SZ + ks * 2048 + lane * 16;
            i32x4 lo = *(const i32x4*)a;
            i32x4 hi = *(const i32x4*)(a + 1024);
            af[x] = __builtin_shufflevector(lo, hi, 0, 1, 2, 3, 4, 5, 6, 7);
            const unsigned char* b = Bs + (wj * 4 + x) * GROUP_SZ + ks * 2048 + lane * 16;
            i32x4 blo = *(const i32x4*)b;
            i32x4 bhi = *(const i32x4*)(b + 1024);
            bf[x] = __builtin_shufflevector(blo, bhi, 0, 1, 2, 3, 4, 5, 6, 7);
        }
        #pragma unroll
        for (int mt = 0; mt < 4; ++mt)
            #pragma unroll
            for (int nt = 0; nt < 4; ++nt)
                acc[mt][nt] = __builtin_amdgcn_mfma_scale_f32_16x16x128_f8f6f4(
                    af[mt], bf[nt], acc[mt][nt], 0, 0, 0, 127, 0, 127);
    }

    float cj[4];
    #pragma unroll
    for (int nt = 0; nt < 4; ++nt)
        cj[nt] = -0.5f * LOG2E * sq[j0 + wj * 64 + nt * 16 + col];

    float local = 0.f;
    if (bi != bj) {
        #pragma unroll
        for (int mt = 0; mt < 4; ++mt)
            #pragma unroll
            for (int r = 0; r < 4; ++r) {
                const float ci = -0.5f * LOG2E * sq[i0 + wi * 64 + mt * 16 + q * 4 + r];
                #pragma unroll
                for (int nt = 0; nt < 4; ++nt)
                    local += exp2f(fmaf(acc[mt][nt][r], LOG2E, ci) + cj[nt]);
            }
        local *= 2.f;
    } else {
        #pragma unroll
        for (int mt = 0; mt < 4; ++mt)
            #pragma unroll
            for (int r = 0; r < 4; ++r) {
                const int li = wi * 64 + mt * 16 + q * 4 + r;
                const float ci = -0.5f * LOG2E * sq[i0 + li];
                #pragma unroll
                for (int nt = 0; nt < 4; ++nt) {
                    const int lj = wj * 64 + nt * 16 + col;
                    float arg = fminf(fmaf(acc[mt][nt][r], LOG2E, ci) + cj[nt], 0.f);
                    local += (li == lj) ? 1.0f : exp2f(arg);
                }
            }
    }

    #pragma unroll
    for (int off = 32; off > 0; off >>= 1) local += __shfl_xor(local, off, 64);
    __syncthreads();
    float* red = (float*)As;
    if (lane == 0) red[wave] = local;
    __syncthreads();
    if (t == 0) partialsA[blockIdx.x] = red[0] + red[1] + red[2] + red[3];
}

__global__ __launch_bounds__(256) void final_kernel(const float* __restrict__ partialsA,
                                                    const float* __restrict__ partialsB,
                                                    float* __restrict__ out) {
    __shared__ double redA[4], redB[4];
    const int t = threadIdx.x;
    double sa = 0.0, sb = 0.0;
    for (int i = t; i < NTILES; i += 256) sa += (double)partialsA[i];
    for (int i = t; i < NPREP; i += 256) sb += (double)partialsB[i];
    #pragma unroll
    for (int off = 32; off > 0; off >>= 1) {
        sa += __shfl_xor(sa, off, 64);
        sb += __shfl_xor(sb, off, 64);
    }
    if ((t & 63) == 0) { redA[t >> 6] = sa; redB[t >> 6] = sb; }
    __syncthreads();
    if (t == 0) {
        double A = redA[0] + redA[1] + redA[2] + redA[3];
        double B = redB[0] + redB[1] + redB[2] + redB[3];
        double term_a = A / ((double)N * (double)N);
        double coeff_b = ldexp(1.0, -128);
        double term_c = 1.0;
        for (int i = 0; i < 128; ++i) term_c /= 3.0;
        out[0] = (float)(term_a - 2.0 * coeff_b * (B / (double)N) + term_c);
    }
}

extern "C" void kernel_launch(void* const* d_in, const int* in_sizes, int n_in,
                              void* d_out, int out_size, void* d_ws, size_t ws_size,
                              hipStream_t stream) {
    const float* z = (const float*)d_in[0];
    float* pA_fb = (float*)((char*)d_ws + WS_PAFB_OFF);
    float* pB_fb = (float*)((char*)d_ws + WS_PBFB_OFF);
    float* coopA = (float*)((char*)d_ws + WS_CA_OFF);
    float* coopB = (float*)((char*)d_ws + WS_CB_OFF);
    float* sq = (float*)((char*)d_ws + WS_SQ_OFF);
    unsigned char* zb8 = (unsigned char*)((char*)d_ws + WS_ZB_OFF);
    float* out = (float*)d_out;

    void* args[] = {(void*)&z, (void*)&zb8, (void*)&sq,
                    (void*)&coopA, (void*)&coopB, (void*)&out};
    hipError_t e = hipLaunchCooperativeKernel((const void*)coop_kernel, dim3(NCOOP),
                                              dim3(256), args, 0, stream);
    if (e != hipSuccess) {
        // deterministic fallback: proven 3-kernel path
        hipLaunchKernelGGL(prep_kernel, dim3(NPREP), dim3(256), 0, stream, z, zb8, sq, pB_fb);
        hipLaunchKernelGGL(pair_mfma_kernel, dim3(NTILES), dim3(256), 0, stream, zb8, sq, pA_fb);
        hipLaunchKernelGGL(final_kernel, dim3(1), dim3(256), 0, stream, pA_fb, pB_fb, out);
    }
}